// Round 7
// baseline (1814.011 us; speedup 1.0000x reference)
//
#include <hip/hip_runtime.h>

// Problem constants
#define NB 16
#define NH 64
#define NW 64
#define ND 128
#define NK 4096
#define NROWS (NB * NH * NW)        // 65536
#define NSLICE 4
#define SLICE_K (NK / NSLICE)       // 1024
#define KTILE 16
#define OUT_ELEMS (NB * ND * NH * NW)  // 8388608
#define MARGIN_F 0.05f

typedef short bf16x8 __attribute__((ext_vector_type(8)));
typedef float f32x4 __attribute__((ext_vector_type(4)));

__device__ __forceinline__ unsigned short f2bf_rne(float x) {
    unsigned int u = __float_as_uint(x);
    u += 0x7FFFu + ((u >> 16) & 1u);
    return (unsigned short)(u >> 16);
}
__device__ __forceinline__ float bf2f(unsigned short h) {
    return __uint_as_float(((unsigned int)h) << 16);
}

// ---------------------------------------------------------------------------
// Kernel 1: emb prep — enorm[k] = ||emb[k]||^2 (fp32 exact) + split-bf16
// e_hi/e_lo. One wave per code.
// ---------------------------------------------------------------------------
__global__ void emb_prep_kernel(const float* __restrict__ emb,
                                float* __restrict__ enorm,
                                unsigned short* __restrict__ e_hi,
                                unsigned short* __restrict__ e_lo) {
    int wave = (blockIdx.x * blockDim.x + threadIdx.x) >> 6;
    int lane = threadIdx.x & 63;
    if (wave >= NK) return;
    const float* e = emb + (size_t)wave * ND;
    float a = e[lane];
    float b = e[lane + 64];
    unsigned short ah = f2bf_rne(a), bh = f2bf_rne(b);
    e_hi[(size_t)wave * ND + lane] = ah;
    e_hi[(size_t)wave * ND + lane + 64] = bh;
    e_lo[(size_t)wave * ND + lane] = f2bf_rne(a - bf2f(ah));
    e_lo[(size_t)wave * ND + lane + 64] = f2bf_rne(b - bf2f(bh));
    float s = a * a + b * b;
#pragma unroll
    for (int off = 32; off > 0; off >>= 1) s += __shfl_down(s, off, 64);
    if (lane == 0) enorm[wave] = s;
}

// ---------------------------------------------------------------------------
// Kernel 2: MFMA argmin. Block = 64 rows x all 4096 codes; 4 waves take
// 1024-code slices. z staged once to LDS as split-bf16 planes (stride 136
// ushort = 272B rows: 16B-aligned, uniform bank spread for the A-frag
// ds_read_b128 pattern). Hot n-loop has NO barrier. dot = hi*hi+hi*lo+lo*hi
// (err <= ~2.5e-3 per score). Per-lane best1/idx/best2 per (mi,reg) row
// slot; rows with margin < MARGIN_F appended to rescue list.
// MFMA 16x16x32 bf16 layouts (guide-verified): A[m=lane&15][k=quad*8+j],
// B[n=lane&15][k=quad*8+j], D[n=lane&15][m=quad*4+reg].
// Remat-safe: loads die within one kk iter; live state = acc/tracking.
// ---------------------------------------------------------------------------
#define ZST 136   // LDS row stride in ushort

__global__ void __launch_bounds__(256, 2)
mfma_argmin_kernel(const float* __restrict__ z,
                   const unsigned short* __restrict__ e_hi,
                   const unsigned short* __restrict__ e_lo,
                   const float* __restrict__ enorm,
                   int* __restrict__ idx_out,
                   int* __restrict__ rcount,
                   int* __restrict__ rlist) {
    __shared__ unsigned short zh[64 * ZST];
    __shared__ unsigned short zl[64 * ZST];
    __shared__ float redb1[NSLICE * 64];
    __shared__ float redb2[NSLICE * 64];
    __shared__ int redi1[NSLICE * 64];

    const int bid = blockIdx.x;
    const int rowbase = bid * 64;
    const int t = threadIdx.x;

    // Stage + split z tile: 2048 float4 coalesced reads, convert to hi/lo.
    const float4* zg = (const float4*)(z + (size_t)rowbase * ND);
#pragma unroll
    for (int q = 0; q < 8; q++) {
        int i = t + 256 * q;               // 0..2047
        float4 v = zg[i];
        int r = i >> 5;
        int c4 = (i & 31) << 2;
        unsigned short h0 = f2bf_rne(v.x), h1 = f2bf_rne(v.y),
                       h2 = f2bf_rne(v.z), h3 = f2bf_rne(v.w);
        ushort4 hv = make_ushort4(h0, h1, h2, h3);
        ushort4 lv = make_ushort4(f2bf_rne(v.x - bf2f(h0)),
                                  f2bf_rne(v.y - bf2f(h1)),
                                  f2bf_rne(v.z - bf2f(h2)),
                                  f2bf_rne(v.w - bf2f(h3)));
        *(ushort4*)&zh[r * ZST + c4] = hv;
        *(ushort4*)&zl[r * ZST + c4] = lv;
    }
    __syncthreads();

    const int lane = t & 63;
    const int wid = __builtin_amdgcn_readfirstlane(t >> 6);
    const int quad = lane >> 4;
    const int c = lane & 15;
    const int n0 = wid * SLICE_K;

    // Per-lane tracking: 16 row slots (mi,reg), row = mi*16 + quad*4 + reg
    float b1[4][4], b2[4][4];
    int i1[4][4];
#pragma unroll
    for (int mi = 0; mi < 4; mi++)
#pragma unroll
        for (int r = 0; r < 4; r++) { b1[mi][r] = 3.4e38f; b2[mi][r] = 3.4e38f; i1[mi][r] = 0; }

    const int aoff = c * ZST + quad * 8;           // ushort index base for A frags
    const unsigned short* pbh = e_hi + c * ND + quad * 8;
    const unsigned short* pbl = e_lo + c * ND + quad * 8;

    for (int nb = n0; nb < n0 + SLICE_K; nb += 64) {   // 16 groups of 64 codes
        f32x4 acc[4][4];
#pragma unroll
        for (int mi = 0; mi < 4; mi++)
#pragma unroll
            for (int ni = 0; ni < 4; ni++) acc[mi][ni] = (f32x4){0.f, 0.f, 0.f, 0.f};

#pragma unroll
        for (int kk = 0; kk < 4; kk++) {
            bf16x8 ah[4], al[4], bh[4], bl[4];
#pragma unroll
            for (int mi = 0; mi < 4; mi++) {
                ah[mi] = *(const bf16x8*)&zh[aoff + mi * (16 * ZST) + kk * 32];
                al[mi] = *(const bf16x8*)&zl[aoff + mi * (16 * ZST) + kk * 32];
            }
#pragma unroll
            for (int ni = 0; ni < 4; ni++) {
                size_t boff = (size_t)(nb + ni * 16) * ND + kk * 32;
                bh[ni] = *(const bf16x8*)(pbh + boff);
                bl[ni] = *(const bf16x8*)(pbl + boff);
            }
#pragma unroll
            for (int mi = 0; mi < 4; mi++)
#pragma unroll
                for (int ni = 0; ni < 4; ni++) {
                    acc[mi][ni] = __builtin_amdgcn_mfma_f32_16x16x32_bf16(ah[mi], bh[ni], acc[mi][ni], 0, 0, 0);
                    acc[mi][ni] = __builtin_amdgcn_mfma_f32_16x16x32_bf16(ah[mi], bl[ni], acc[mi][ni], 0, 0, 0);
                    acc[mi][ni] = __builtin_amdgcn_mfma_f32_16x16x32_bf16(al[mi], bh[ni], acc[mi][ni], 0, 0, 0);
                }
        }

        // scores + tracking update
#pragma unroll
        for (int ni = 0; ni < 4; ni++) {
            int n = nb + ni * 16 + c;                  // this lane's code
            float en = enorm[n];
#pragma unroll
            for (int mi = 0; mi < 4; mi++)
#pragma unroll
                for (int r = 0; r < 4; r++) {
                    float s = fmaf(-2.0f, acc[mi][ni][r], en);
                    if (s < b1[mi][r]) { b2[mi][r] = b1[mi][r]; b1[mi][r] = s; i1[mi][r] = n; }
                    else if (s < b2[mi][r]) b2[mi][r] = s;
                }
        }
    }

    // Cross-lane merge within each 16-lane column group (xor 1,2,4,8)
#pragma unroll
    for (int off = 1; off < 16; off <<= 1) {
#pragma unroll
        for (int mi = 0; mi < 4; mi++)
#pragma unroll
            for (int r = 0; r < 4; r++) {
                float ob1 = __shfl_xor(b1[mi][r], off, 64);
                float ob2 = __shfl_xor(b2[mi][r], off, 64);
                int oi1 = __shfl_xor(i1[mi][r], off, 64);
                float lo = fminf(b1[mi][r], ob1);
                float hi = fmaxf(b1[mi][r], ob1);
                b2[mi][r] = fminf(fminf(b2[mi][r], ob2), hi);
                i1[mi][r] = (ob1 < b1[mi][r]) ? oi1 : i1[mi][r];
                b1[mi][r] = lo;
            }
    }

    if (c == 0) {
#pragma unroll
        for (int mi = 0; mi < 4; mi++)
#pragma unroll
            for (int r = 0; r < 4; r++) {
                int row = mi * 16 + quad * 4 + r;
                redb1[wid * 64 + row] = b1[mi][r];
                redb2[wid * 64 + row] = b2[mi][r];
                redi1[wid * 64 + row] = i1[mi][r];
            }
    }
    __syncthreads();

    if (t < 64) {
        float B1 = redb1[t], B2 = redb2[t];
        int I1 = redi1[t];
#pragma unroll
        for (int sl = 1; sl < NSLICE; sl++) {
            float ob1 = redb1[sl * 64 + t];
            float ob2 = redb2[sl * 64 + t];
            int oi1 = redi1[sl * 64 + t];
            float lo = fminf(B1, ob1);
            float hi = fmaxf(B1, ob1);
            B2 = fminf(fminf(B2, ob2), hi);
            I1 = (ob1 < B1) ? oi1 : I1;     // strict <, ascending slices
            B1 = lo;
        }
        idx_out[rowbase + t] = I1;
        if (B2 - B1 < MARGIN_F) {
            int p = atomicAdd(rcount, 1);
            rlist[p] = rowbase + t;
        }
    }
}

// ---------------------------------------------------------------------------
// Kernel 3: exact fp32 rescue for small-margin rows. Fixed 64-block grid,
// grid-stride over the compacted rescue list. Body = R6's verified argmin
// (named scalar accumulators, transposed-LDS z), rows gathered via rlist.
// ---------------------------------------------------------------------------
#define EFMA(KK) { \
    const float4* e4 = emb4 + (((size_t)(kb + KK)) << 5) + (dc << 2); \
    float4 e0 = e4[0], e1 = e4[1], e2 = e4[2], e3 = e4[3]; \
    acc##KK = fmaf(zc0.x, e0.x, acc##KK); acc##KK = fmaf(zc0.y, e0.y, acc##KK); \
    acc##KK = fmaf(zc1.x, e0.z, acc##KK); acc##KK = fmaf(zc1.y, e0.w, acc##KK); \
    acc##KK = fmaf(zc2.x, e1.x, acc##KK); acc##KK = fmaf(zc2.y, e1.y, acc##KK); \
    acc##KK = fmaf(zc3.x, e1.z, acc##KK); acc##KK = fmaf(zc3.y, e1.w, acc##KK); \
    acc##KK = fmaf(zc4.x, e2.x, acc##KK); acc##KK = fmaf(zc4.y, e2.y, acc##KK); \
    acc##KK = fmaf(zc5.x, e2.z, acc##KK); acc##KK = fmaf(zc5.y, e2.w, acc##KK); \
    acc##KK = fmaf(zc6.x, e3.x, acc##KK); acc##KK = fmaf(zc6.y, e3.y, acc##KK); \
    acc##KK = fmaf(zc7.x, e3.z, acc##KK); acc##KK = fmaf(zc7.y, e3.w, acc##KK); }

#define SEL(KK) { \
    float s = fmaf(-2.0f, acc##KK, enorm[kb + KK]); \
    if (s < best) { best = s; bidx = kb + KK; } }

__global__ void __launch_bounds__(256, 4)
rescue_kernel(const float* __restrict__ z,
              const float* __restrict__ emb,
              const float* __restrict__ enorm,
              const int* __restrict__ rcount,
              const int* __restrict__ rlist,
              int* __restrict__ idx_out) {
    __shared__ float2 zs2[64 * 65];
    __shared__ int ids[64];
    __shared__ float red_min[NSLICE * 64];
    __shared__ int red_idx[NSLICE * 64];

    const int t = threadIdx.x;
    const int lane = t & 63;
    const int wid = __builtin_amdgcn_readfirstlane(t >> 6);
    const int cnt = *rcount;

    for (int base = blockIdx.x * 64; base < cnt; base += 64 * 64) {
        if (t < 64) {
            int j = base + t;
            ids[t] = rlist[j < cnt ? j : cnt - 1];
        }
        __syncthreads();

        // stage gathered rows, transposed
#pragma unroll
        for (int q = 0; q < 16; q++) {
            int g = t + 256 * q;
            int r = g >> 6;
            int d2 = g & 63;
            int row = ids[r];
            zs2[d2 * 65 + r] = ((const float2*)(z + (size_t)row * ND))[d2];
        }
        __syncthreads();

        const float4* emb4 = (const float4*)emb;
        float best = 3.4e38f;
        int bidx = 0;
        const int k0 = wid * SLICE_K;

        for (int kt = 0; kt < SLICE_K / KTILE; kt++) {
            const int kb = k0 + kt * KTILE;
            float acc0 = 0.f, acc1 = 0.f, acc2 = 0.f, acc3 = 0.f;
            float acc4 = 0.f, acc5 = 0.f, acc6 = 0.f, acc7 = 0.f;
            float acc8 = 0.f, acc9 = 0.f, acc10 = 0.f, acc11 = 0.f;
            float acc12 = 0.f, acc13 = 0.f, acc14 = 0.f, acc15 = 0.f;

            for (int dc = 0; dc < 8; dc++) {
                const float2* zb = &zs2[(dc * 8) * 65 + lane];
                float2 zc0 = zb[0 * 65], zc1 = zb[1 * 65], zc2 = zb[2 * 65],
                       zc3 = zb[3 * 65], zc4 = zb[4 * 65], zc5 = zb[5 * 65],
                       zc6 = zb[6 * 65], zc7 = zb[7 * 65];
                EFMA(0)  EFMA(1)  EFMA(2)  EFMA(3)
                EFMA(4)  EFMA(5)  EFMA(6)  EFMA(7)
                EFMA(8)  EFMA(9)  EFMA(10) EFMA(11)
                EFMA(12) EFMA(13) EFMA(14) EFMA(15)
            }

            SEL(0)  SEL(1)  SEL(2)  SEL(3)
            SEL(4)  SEL(5)  SEL(6)  SEL(7)
            SEL(8)  SEL(9)  SEL(10) SEL(11)
            SEL(12) SEL(13) SEL(14) SEL(15)
        }

        red_min[wid * 64 + lane] = best;
        red_idx[wid * 64 + lane] = bidx;
        __syncthreads();

        if (wid == 0) {
            float bm = red_min[lane];
            int bi = red_idx[lane];
#pragma unroll
            for (int sl = 1; sl < NSLICE; sl++) {
                float m = red_min[sl * 64 + lane];
                int i2 = red_idx[sl * 64 + lane];
                if (m < bm) { bm = m; bi = i2; }
            }
            if (base + lane < cnt) idx_out[ids[lane]] = bi;
        }
        __syncthreads();   // protect LDS before next iteration
    }
}

// ---------------------------------------------------------------------------
// Kernel 4: gather + loss partial + transposed write (unchanged from R6).
// ---------------------------------------------------------------------------
__global__ void out_kernel(const float* __restrict__ z,
                           const float* __restrict__ emb,
                           const int* __restrict__ idx,
                           float* __restrict__ out,
                           float* __restrict__ losspart) {
    __shared__ float zq[64 * 129];
    __shared__ int ids[64];
    __shared__ float redl[4];

    const int bid = blockIdx.x;
    const int b = bid >> 6;
    const int h = bid & 63;
    const int rowbase = bid * 64;
    const int t = threadIdx.x;

    if (t < 64) ids[t] = idx[rowbase + t];
    __syncthreads();

    const int d = t & 127;
    const int w0 = t >> 7;
    float lsum = 0.f;
#pragma unroll
    for (int wq = 0; wq < 32; wq++) {
        int w = w0 + 2 * wq;
        float e = emb[(size_t)ids[w] * ND + d];
        float zv = z[((size_t)(rowbase + w)) * ND + d];
        float df = e - zv;
        lsum = fmaf(df, df, lsum);
        zq[w * 129 + d] = e;
    }
#pragma unroll
    for (int off = 32; off > 0; off >>= 1) lsum += __shfl_down(lsum, off, 64);
    if ((t & 63) == 0) redl[t >> 6] = lsum;
    __syncthreads();
    if (t == 0) losspart[bid] = redl[0] + redl[1] + redl[2] + redl[3];

    const int w = t & 63;
    const int dq = t >> 6;
#pragma unroll
    for (int dd0 = 0; dd0 < 32; dd0++) {
        int dd = dq + 4 * dd0;
        out[(((size_t)b * ND + dd) * NH + h) * NW + w] = zq[w * 129 + dd];
    }
}

// ---------------------------------------------------------------------------
// Kernel 5: final loss reduce
// ---------------------------------------------------------------------------
__global__ void loss_kernel(const float* __restrict__ losspart,
                            float* __restrict__ out) {
    __shared__ float redl[4];
    const int t = threadIdx.x;
    float s = 0.f;
#pragma unroll
    for (int i = 0; i < 4; i++) s += losspart[t + 256 * i];
#pragma unroll
    for (int off = 32; off > 0; off >>= 1) s += __shfl_down(s, off, 64);
    if ((t & 63) == 0) redl[t >> 6] = s;
    __syncthreads();
    if (t == 0) {
        float total = redl[0] + redl[1] + redl[2] + redl[3];
        out[OUT_ELEMS] = 1.25f * total / (float)OUT_ELEMS;
    }
}

// ---------------------------------------------------------------------------
extern "C" void kernel_launch(void* const* d_in, const int* in_sizes, int n_in,
                              void* d_out, int out_size, void* d_ws, size_t ws_size,
                              hipStream_t stream) {
    const float* z = (const float*)d_in[0];      // [16,64,64,128] fp32
    const float* emb = (const float*)d_in[1];    // [4096,128] fp32
    float* out = (float*)d_out;                  // 8388608 + 1 fp32

    char* ws = (char*)d_ws;
    int* ws_idx = (int*)ws;                                   // 256 KB
    float* ws_enorm = (float*)(ws + (256 << 10));             // 16 KB
    float* ws_losspart = (float*)(ws + (272 << 10));          // 4 KB
    int* ws_rcount = (int*)(ws + (276 << 10));                // 256 B
    int* ws_rlist = (int*)(ws + (277 << 10));                 // 256 KB
    unsigned short* ws_ehi = (unsigned short*)(ws + (533 << 10));   // 1 MB
    unsigned short* ws_elo = (unsigned short*)(ws + (1557 << 10));  // 1 MB

    hipMemsetAsync(ws_rcount, 0, sizeof(int), stream);
    emb_prep_kernel<<<NK / 4, 256, 0, stream>>>(emb, ws_enorm, ws_ehi, ws_elo);
    mfma_argmin_kernel<<<NROWS / 64, 256, 0, stream>>>(z, ws_ehi, ws_elo,
                                                       ws_enorm, ws_idx,
                                                       ws_rcount, ws_rlist);
    rescue_kernel<<<64, 256, 0, stream>>>(z, emb, ws_enorm, ws_rcount,
                                          ws_rlist, ws_idx);
    out_kernel<<<NB * NH, 256, 0, stream>>>(z, emb, ws_idx, out, ws_losspart);
    loss_kernel<<<1, 256, 0, stream>>>(ws_losspart, out);
}

// Round 8
// 872.235 us; speedup vs baseline: 2.0797x; 2.0797x over previous
//
#include <hip/hip_runtime.h>

// Problem constants
#define NB 16
#define NH 64
#define NW 64
#define ND 128
#define NK 4096
#define NROWS (NB * NH * NW)        // 65536
#define NSLICE 4
#define SLICE_K (NK / NSLICE)       // 1024
#define OUT_ELEMS (NB * ND * NH * NW)  // 8388608
#define MARGIN_F 0.05f

typedef short bf16x8 __attribute__((ext_vector_type(8)));
typedef float f32x4 __attribute__((ext_vector_type(4)));

__device__ __forceinline__ unsigned short f2bf_rne(float x) {
    unsigned int u = __float_as_uint(x);
    u += 0x7FFFu + ((u >> 16) & 1u);
    return (unsigned short)(u >> 16);
}
__device__ __forceinline__ float bf2f(unsigned short h) {
    return __uint_as_float(((unsigned int)h) << 16);
}

// ---------------------------------------------------------------------------
// Kernel 1: emb prep — enorm[k] = ||emb[k]||^2 (fp32 exact) + split-bf16
// e_hi/e_lo. One wave per code.
// ---------------------------------------------------------------------------
__global__ void emb_prep_kernel(const float* __restrict__ emb,
                                float* __restrict__ enorm,
                                unsigned short* __restrict__ e_hi,
                                unsigned short* __restrict__ e_lo) {
    int wave = (blockIdx.x * blockDim.x + threadIdx.x) >> 6;
    int lane = threadIdx.x & 63;
    if (wave >= NK) return;
    const float* e = emb + (size_t)wave * ND;
    float a = e[lane];
    float b = e[lane + 64];
    unsigned short ah = f2bf_rne(a), bh = f2bf_rne(b);
    e_hi[(size_t)wave * ND + lane] = ah;
    e_hi[(size_t)wave * ND + lane + 64] = bh;
    e_lo[(size_t)wave * ND + lane] = f2bf_rne(a - bf2f(ah));
    e_lo[(size_t)wave * ND + lane + 64] = f2bf_rne(b - bf2f(bh));
    float s = a * a + b * b;
#pragma unroll
    for (int off = 32; off > 0; off >>= 1) s += __shfl_down(s, off, 64);
    if (lane == 0) enorm[wave] = s;
}

// ---------------------------------------------------------------------------
// Kernel 2: MFMA argmin (unchanged from R7 — passed correctness, not in
// top-5 dispatches). Block = 64 rows x 4096 codes; 4 waves x 1024-code
// slices; z in LDS as split-bf16 planes; dot = hi*hi+hi*lo+lo*hi; rows with
// best2-best1 < MARGIN_F go to the exact-rescue list.
// ---------------------------------------------------------------------------
#define ZST 136   // LDS row stride in ushort

__global__ void __launch_bounds__(256, 2)
mfma_argmin_kernel(const float* __restrict__ z,
                   const unsigned short* __restrict__ e_hi,
                   const unsigned short* __restrict__ e_lo,
                   const float* __restrict__ enorm,
                   int* __restrict__ idx_out,
                   int* __restrict__ rcount,
                   int* __restrict__ rlist) {
    __shared__ unsigned short zh[64 * ZST];
    __shared__ unsigned short zl[64 * ZST];
    __shared__ float redb1[NSLICE * 64];
    __shared__ float redb2[NSLICE * 64];
    __shared__ int redi1[NSLICE * 64];

    const int bid = blockIdx.x;
    const int rowbase = bid * 64;
    const int t = threadIdx.x;

    const float4* zg = (const float4*)(z + (size_t)rowbase * ND);
#pragma unroll
    for (int q = 0; q < 8; q++) {
        int i = t + 256 * q;               // 0..2047
        float4 v = zg[i];
        int r = i >> 5;
        int c4 = (i & 31) << 2;
        unsigned short h0 = f2bf_rne(v.x), h1 = f2bf_rne(v.y),
                       h2 = f2bf_rne(v.z), h3 = f2bf_rne(v.w);
        ushort4 hv = make_ushort4(h0, h1, h2, h3);
        ushort4 lv = make_ushort4(f2bf_rne(v.x - bf2f(h0)),
                                  f2bf_rne(v.y - bf2f(h1)),
                                  f2bf_rne(v.z - bf2f(h2)),
                                  f2bf_rne(v.w - bf2f(h3)));
        *(ushort4*)&zh[r * ZST + c4] = hv;
        *(ushort4*)&zl[r * ZST + c4] = lv;
    }
    __syncthreads();

    const int lane = t & 63;
    const int wid = __builtin_amdgcn_readfirstlane(t >> 6);
    const int quad = lane >> 4;
    const int c = lane & 15;
    const int n0 = wid * SLICE_K;

    float b1[4][4], b2[4][4];
    int i1[4][4];
#pragma unroll
    for (int mi = 0; mi < 4; mi++)
#pragma unroll
        for (int r = 0; r < 4; r++) { b1[mi][r] = 3.4e38f; b2[mi][r] = 3.4e38f; i1[mi][r] = 0; }

    const int aoff = c * ZST + quad * 8;
    const unsigned short* pbh = e_hi + c * ND + quad * 8;
    const unsigned short* pbl = e_lo + c * ND + quad * 8;

    for (int nb = n0; nb < n0 + SLICE_K; nb += 64) {
        f32x4 acc[4][4];
#pragma unroll
        for (int mi = 0; mi < 4; mi++)
#pragma unroll
            for (int ni = 0; ni < 4; ni++) acc[mi][ni] = (f32x4){0.f, 0.f, 0.f, 0.f};

#pragma unroll
        for (int kk = 0; kk < 4; kk++) {
            bf16x8 ah[4], al[4], bh[4], bl[4];
#pragma unroll
            for (int mi = 0; mi < 4; mi++) {
                ah[mi] = *(const bf16x8*)&zh[aoff + mi * (16 * ZST) + kk * 32];
                al[mi] = *(const bf16x8*)&zl[aoff + mi * (16 * ZST) + kk * 32];
            }
#pragma unroll
            for (int ni = 0; ni < 4; ni++) {
                size_t boff = (size_t)(nb + ni * 16) * ND + kk * 32;
                bh[ni] = *(const bf16x8*)(pbh + boff);
                bl[ni] = *(const bf16x8*)(pbl + boff);
            }
#pragma unroll
            for (int mi = 0; mi < 4; mi++)
#pragma unroll
                for (int ni = 0; ni < 4; ni++) {
                    acc[mi][ni] = __builtin_amdgcn_mfma_f32_16x16x32_bf16(ah[mi], bh[ni], acc[mi][ni], 0, 0, 0);
                    acc[mi][ni] = __builtin_amdgcn_mfma_f32_16x16x32_bf16(ah[mi], bl[ni], acc[mi][ni], 0, 0, 0);
                    acc[mi][ni] = __builtin_amdgcn_mfma_f32_16x16x32_bf16(al[mi], bh[ni], acc[mi][ni], 0, 0, 0);
                }
        }

#pragma unroll
        for (int ni = 0; ni < 4; ni++) {
            int n = nb + ni * 16 + c;
            float en = enorm[n];
#pragma unroll
            for (int mi = 0; mi < 4; mi++)
#pragma unroll
                for (int r = 0; r < 4; r++) {
                    float s = fmaf(-2.0f, acc[mi][ni][r], en);
                    if (s < b1[mi][r]) { b2[mi][r] = b1[mi][r]; b1[mi][r] = s; i1[mi][r] = n; }
                    else if (s < b2[mi][r]) b2[mi][r] = s;
                }
        }
    }

#pragma unroll
    for (int off = 1; off < 16; off <<= 1) {
#pragma unroll
        for (int mi = 0; mi < 4; mi++)
#pragma unroll
            for (int r = 0; r < 4; r++) {
                float ob1 = __shfl_xor(b1[mi][r], off, 64);
                float ob2 = __shfl_xor(b2[mi][r], off, 64);
                int oi1 = __shfl_xor(i1[mi][r], off, 64);
                float lo = fminf(b1[mi][r], ob1);
                float hi = fmaxf(b1[mi][r], ob1);
                b2[mi][r] = fminf(fminf(b2[mi][r], ob2), hi);
                i1[mi][r] = (ob1 < b1[mi][r]) ? oi1 : i1[mi][r];
                b1[mi][r] = lo;
            }
    }

    if (c == 0) {
#pragma unroll
        for (int mi = 0; mi < 4; mi++)
#pragma unroll
            for (int r = 0; r < 4; r++) {
                int row = mi * 16 + quad * 4 + r;
                redb1[wid * 64 + row] = b1[mi][r];
                redb2[wid * 64 + row] = b2[mi][r];
                redi1[wid * 64 + row] = i1[mi][r];
            }
    }
    __syncthreads();

    if (t < 64) {
        float B1 = redb1[t], B2 = redb2[t];
        int I1 = redi1[t];
#pragma unroll
        for (int sl = 1; sl < NSLICE; sl++) {
            float ob1 = redb1[sl * 64 + t];
            float ob2 = redb2[sl * 64 + t];
            int oi1 = redi1[sl * 64 + t];
            float lo = fminf(B1, ob1);
            float hi = fmaxf(B1, ob1);
            B2 = fminf(fminf(B2, ob2), hi);
            I1 = (ob1 < B1) ? oi1 : I1;
            B1 = lo;
        }
        idx_out[rowbase + t] = I1;
        if (B2 - B1 < MARGIN_F) {
            int p = atomicAdd(rcount, 1);
            rlist[p] = rowbase + t;
        }
    }
}

// ---------------------------------------------------------------------------
// Kernel 3: exact fp32 rescue, REBUILT for tiny-N (R7: old 64-rows/block
// shape ran ~8 blocks at 1 wave/SIMD, s_load latency-bound, 1300us).
// One block per rescue ROW; 4096 codes spread over 256 threads (k=j*256+t),
// per-lane global float4 e-loads give deep MLP; z row broadcast from LDS.
// Argmin ties: per-thread k ascending + strict <; merges carry explicit
// smaller-index tie-break => first-index semantics.
// ---------------------------------------------------------------------------
__global__ void __launch_bounds__(256, 4)
rescue_kernel(const float* __restrict__ z,
              const float* __restrict__ emb,
              const float* __restrict__ enorm,
              const int* __restrict__ rcount,
              const int* __restrict__ rlist,
              int* __restrict__ idx_out) {
    __shared__ float zs[ND];
    __shared__ float rbest[4];
    __shared__ int ridx[4];

    const int t = threadIdx.x;
    const int cnt = *rcount;

    for (int i = blockIdx.x; i < cnt; i += gridDim.x) {
        const int row = rlist[i];
        if (t < 32) ((float4*)zs)[t] = ((const float4*)(z + (size_t)row * ND))[t];
        __syncthreads();

        float best = 3.4e38f;
        int bidx = 0;
        for (int j = 0; j < 16; j++) {
            int k = j * 256 + t;                       // ascending per thread
            const float4* e4 = (const float4*)(emb + (size_t)k * ND);
            float a0 = 0.f, a1 = 0.f, a2 = 0.f, a3 = 0.f;
#pragma unroll
            for (int d = 0; d < 32; d++) {
                float4 ev = e4[d];
                float4 zv = ((const float4*)zs)[d];    // LDS broadcast
                a0 = fmaf(zv.x, ev.x, a0);
                a1 = fmaf(zv.y, ev.y, a1);
                a2 = fmaf(zv.z, ev.z, a2);
                a3 = fmaf(zv.w, ev.w, a3);
            }
            float s = fmaf(-2.0f, (a0 + a1) + (a2 + a3), enorm[k]);
            if (s < best) { best = s; bidx = k; }      // strict < => first idx
        }

#pragma unroll
        for (int off = 32; off > 0; off >>= 1) {
            float ob = __shfl_down(best, off, 64);
            int oi = __shfl_down(bidx, off, 64);
            if (ob < best || (ob == best && oi < bidx)) { best = ob; bidx = oi; }
        }
        if ((t & 63) == 0) { rbest[t >> 6] = best; ridx[t >> 6] = bidx; }
        __syncthreads();
        if (t == 0) {
            float B = rbest[0]; int I = ridx[0];
#pragma unroll
            for (int w2 = 1; w2 < 4; w2++) {
                if (rbest[w2] < B || (rbest[w2] == B && ridx[w2] < I)) {
                    B = rbest[w2]; I = ridx[w2];
                }
            }
            idx_out[row] = I;
        }
        __syncthreads();   // protect zs before next row
    }
}

// ---------------------------------------------------------------------------
// Kernel 4: gather + loss partial + transposed write (unchanged).
// ---------------------------------------------------------------------------
__global__ void out_kernel(const float* __restrict__ z,
                           const float* __restrict__ emb,
                           const int* __restrict__ idx,
                           float* __restrict__ out,
                           float* __restrict__ losspart) {
    __shared__ float zq[64 * 129];
    __shared__ int ids[64];
    __shared__ float redl[4];

    const int bid = blockIdx.x;
    const int b = bid >> 6;
    const int h = bid & 63;
    const int rowbase = bid * 64;
    const int t = threadIdx.x;

    if (t < 64) ids[t] = idx[rowbase + t];
    __syncthreads();

    const int d = t & 127;
    const int w0 = t >> 7;
    float lsum = 0.f;
#pragma unroll
    for (int wq = 0; wq < 32; wq++) {
        int w = w0 + 2 * wq;
        float e = emb[(size_t)ids[w] * ND + d];
        float zv = z[((size_t)(rowbase + w)) * ND + d];
        float df = e - zv;
        lsum = fmaf(df, df, lsum);
        zq[w * 129 + d] = e;
    }
#pragma unroll
    for (int off = 32; off > 0; off >>= 1) lsum += __shfl_down(lsum, off, 64);
    if ((t & 63) == 0) redl[t >> 6] = lsum;
    __syncthreads();
    if (t == 0) losspart[bid] = redl[0] + redl[1] + redl[2] + redl[3];

    const int w = t & 63;
    const int dq = t >> 6;
#pragma unroll
    for (int dd0 = 0; dd0 < 32; dd0++) {
        int dd = dq + 4 * dd0;
        out[(((size_t)b * ND + dd) * NH + h) * NW + w] = zq[w * 129 + dd];
    }
}

// ---------------------------------------------------------------------------
// Kernel 5: final loss reduce
// ---------------------------------------------------------------------------
__global__ void loss_kernel(const float* __restrict__ losspart,
                            float* __restrict__ out) {
    __shared__ float redl[4];
    const int t = threadIdx.x;
    float s = 0.f;
#pragma unroll
    for (int i = 0; i < 4; i++) s += losspart[t + 256 * i];
#pragma unroll
    for (int off = 32; off > 0; off >>= 1) s += __shfl_down(s, off, 64);
    if ((t & 63) == 0) redl[t >> 6] = s;
    __syncthreads();
    if (t == 0) {
        float total = redl[0] + redl[1] + redl[2] + redl[3];
        out[OUT_ELEMS] = 1.25f * total / (float)OUT_ELEMS;
    }
}

// ---------------------------------------------------------------------------
extern "C" void kernel_launch(void* const* d_in, const int* in_sizes, int n_in,
                              void* d_out, int out_size, void* d_ws, size_t ws_size,
                              hipStream_t stream) {
    const float* z = (const float*)d_in[0];      // [16,64,64,128] fp32
    const float* emb = (const float*)d_in[1];    // [4096,128] fp32
    float* out = (float*)d_out;                  // 8388608 + 1 fp32

    char* ws = (char*)d_ws;
    int* ws_idx = (int*)ws;                                   // 256 KB
    float* ws_enorm = (float*)(ws + (256 << 10));             // 16 KB
    float* ws_losspart = (float*)(ws + (272 << 10));          // 4 KB
    int* ws_rcount = (int*)(ws + (276 << 10));                // 256 B
    int* ws_rlist = (int*)(ws + (277 << 10));                 // 256 KB
    unsigned short* ws_ehi = (unsigned short*)(ws + (533 << 10));   // 1 MB
    unsigned short* ws_elo = (unsigned short*)(ws + (1557 << 10));  // 1 MB

    hipMemsetAsync(ws_rcount, 0, sizeof(int), stream);
    emb_prep_kernel<<<NK / 4, 256, 0, stream>>>(emb, ws_enorm, ws_ehi, ws_elo);
    mfma_argmin_kernel<<<NROWS / 64, 256, 0, stream>>>(z, ws_ehi, ws_elo,
                                                       ws_enorm, ws_idx,
                                                       ws_rcount, ws_rlist);
    rescue_kernel<<<1024, 256, 0, stream>>>(z, emb, ws_enorm, ws_rcount,
                                            ws_rlist, ws_idx);
    out_kernel<<<NB * NH, 256, 0, stream>>>(z, emb, ws_idx, out, ws_losspart);
    loss_kernel<<<1, 256, 0, stream>>>(ws_losspart, out);
}